// Round 11
// baseline (50.934 us; speedup 1.0000x reference)
//
#include <hip/hip_runtime.h>
#include <hip/hip_bf16.h>
#include <stdint.h>

typedef __attribute__((ext_vector_type(4))) float f32x4;
typedef __attribute__((ext_vector_type(8))) short bf16x8;

#define NCH  128
#define NREL 8
#define NSEG 32            // ticket counters / glist segments
#define SEGCAP 2048        // nodes per segment (64 hist blocks x 32)

__device__ __forceinline__ unsigned short f2bf(float f) {
    unsigned u = __builtin_bit_cast(unsigned, f);
    u += 0x7fffu + ((u >> 16) & 1u);          // RNE to bf16
    return (unsigned short)(u >> 16);
}

__device__ __forceinline__ bool mask_used(const unsigned char* um, int stride, int s) {
    if (stride == 1) return um[s] != 0;
    if (stride == 4) return ((const int*)um)[s] != 0;
    return ((const long long*)um)[s] != 0;
}

// ---------------------------------------------------------------------------
// K1: W->Wb convert; block 0 zeroes the 32 ticket counters (64B apart) and
// detects used_mask element width -> cn[1].
// ---------------------------------------------------------------------------
__global__ __launch_bounds__(256)
void k_prep(const float* __restrict__ W, unsigned short* __restrict__ Wb,
            int* __restrict__ cn, const unsigned char* __restrict__ um_raw) {
    int o = blockIdx.x * 256 + threadIdx.x;
    if (o < NREL * NCH * NCH) {
        int kk = o & 31;
        int h  = (o >> 5) & (NCH - 1);
        int kt = o >> 12;
        Wb[o] = f2bf(W[(kt * 32 + kk) * NCH + h]);
    }
    if (blockIdx.x == 0) {
        __shared__ unsigned sA, sB;
        const int t = threadIdx.x;
        if (t == 0) { sA = 0; sB = 0; }
        if (t < NSEG) cn[16 + t * 16] = 0;       // ticket counters
        __syncthreads();
        unsigned a = 0, b = 0;
        #pragma unroll 4
        for (int p = t; p < 1024; p += 256) {
            unsigned v = um_raw[p];
            if ((p & 3) != 0) a |= v;
            if ((p & 7) == 4) b |= v;
        }
        if (a) atomicOr(&sA, 1u);
        if (b) atomicOr(&sB, 1u);
        __syncthreads();
        if (t == 0) cn[1] = sA ? 1 : (sB ? 4 : 8);
    }
}

// ---------------------------------------------------------------------------
// K2: 32 nodes/block (2048 blocks). Ballot-classify (no serialized LDS
// atomics), copy cached rows with nontemporal stores, ticket-append the
// non-cached ids into glist segment (blockIdx & 31).
// ---------------------------------------------------------------------------
__global__ __launch_bounds__(256)
void k_hist(const float* __restrict__ hb, const int* __restrict__ hm,
            const int* __restrict__ hs, float* __restrict__ out,
            int* __restrict__ cn, int* __restrict__ glist, int num_node) {
    __shared__ int cList[32], ncList[32];
    __shared__ int nCs, nNCs, gbase;
    const int t = threadIdx.x;
    if (t < 64) {                                  // wave 0 classifies
        const int n = blockIdx.x * 32 + t;
        const bool valid  = (t < 32) && (n < num_node);
        const bool cached = valid && (hs[0] > 0) && (hm[n] != -1);
        const bool nc     = valid && !cached;
        const unsigned long long mC  = __ballot(cached);
        const unsigned long long mNC = __ballot(nc);
        const unsigned long long below = (1ull << t) - 1;
        if (cached) cList[__popcll(mC & below)]   = n;
        if (nc)     ncList[__popcll(mNC & below)] = n;
        if (t == 0) { nCs = __popcll(mC); nNCs = __popcll(mNC); }
    }
    __syncthreads();
    const int myC = nCs, myNC = nNCs;
    const int hw = t >> 5, l = t & 31;
    int   node[4];
    f32x4 v[4];
    #pragma unroll 4
    for (int j = 0; j < 4; ++j) {
        const int i = hw + j * 8;
        node[j] = (i < myC) ? cList[i] : -1;
        if (node[j] >= 0)
            v[j] = *(const f32x4*)(hb + (long)node[j] * NCH + l * 4);
    }
    #pragma unroll 4
    for (int j = 0; j < 4; ++j) {
        if (node[j] >= 0)
            __builtin_nontemporal_store(v[j],
                (f32x4*)(out + (long)node[j] * NCH + l * 4));
    }
    const int seg = blockIdx.x & (NSEG - 1);
    if (t == 0) gbase = atomicAdd(&cn[16 + seg * 16], myNC);
    __syncthreads();
    if (t < myNC) glist[seg * SEGCAP + gbase + t] = ncList[t];
}

// ---------------------------------------------------------------------------
// K3: 512 threads; block j -> segment j&31, group j>>5 (16 nodes).
// ONE NODE PER HALF-WAVE, 16 gathers in flight. __launch_bounds__(512,4)
// caps VGPR at 128 -> 4 waves/SIMD (vs ~3 unconstrained).
// ---------------------------------------------------------------------------
__global__ __launch_bounds__(512, 4)
void k_main(const float* __restrict__ x, const unsigned short* __restrict__ Wb,
            const int* __restrict__ ptr, const int* __restrict__ idx,
            const int* __restrict__ et, const unsigned char* __restrict__ um,
            const int* __restrict__ cn, const int* __restrict__ glist,
            float* __restrict__ out) {
    __shared__ __align__(16) char As[16 * NREL * NCH * 2];   // 32 KB, XOR-swizzled
    __shared__ int   nid[16];
    __shared__ float invdeg[16];

    const int seg   = blockIdx.x & (NSEG - 1);
    const int grp   = blockIdx.x >> 5;
    const int cntS  = cn[16 + seg * 16];
    const int base  = grp * 16;
    if (base >= cntS) return;
    const int mstride = cn[1];
    const int t = threadIdx.x;
    if (t < 16) {
        const int i = base + t;
        nid[t]    = (i < cntS) ? glist[seg * SEGCAP + i] : -1;
        invdeg[t] = 0.0f;
    }
    __syncthreads();

    const int hw    = t >> 5;       // half-wave id 0..15 == node slot
    const int l     = t & 31;       // lane in half-wave; owns channels 4l..4l+3
    const int lbase = t & 32;       // half-wave base within its wave
    const int n     = nid[hw];

    if (n >= 0) {
        const int p0 = ptr[n], p1 = ptr[n + 1];
        const int deg = p1 - p0;
        if (l == 0) invdeg[hw] = (deg > 0) ? 1.0f / (float)deg : 0.0f;
        // lanes 0..15 of this half-wave fetch edge metadata, pack (rel<<24)|src
        int myPk = NREL << 24;
        if (l < 16 && (p0 + l) < p1) {
            const int e  = p0 + l;
            const int s  = idx[e];
            const int tt = et[e];
            myPk = s | (((mask_used(um, mstride, s) && tt >= 0 && tt < NREL)
                         ? tt : NREL) << 24);
        }
        // all 16 row-gathers in flight before any consumption
        int   pk[16];
        f32x4 xv[16];
        #pragma unroll 16
        for (int e = 0; e < 16; ++e) {
            pk[e] = __shfl(myPk, lbase + e, 64);
            xv[e] = *(const f32x4*)(x + (long)(pk[e] & 0xFFFFFF) * NCH + l * 4);
        }
        float acc[NREL][4];
        #pragma unroll
        for (int q = 0; q < NREL; ++q)
            #pragma unroll
            for (int j = 0; j < 4; ++j) acc[q][j] = 0.0f;
        #pragma unroll 16
        for (int e = 0; e < 16; ++e) {
            const int r = pk[e] >> 24;
            #pragma unroll
            for (int q = 0; q < NREL; ++q) {
                const float sel = (r == q) ? 1.0f : 0.0f;
                acc[q][0] += sel * xv[e].x;
                acc[q][1] += sel * xv[e].y;
                acc[q][2] += sel * xv[e].z;
                acc[q][3] += sel * xv[e].w;
            }
        }
        for (int e = p0 + 16; e < p1; ++e) {       // rare: deg > 16
            const int s  = idx[e];
            const int tt = et[e];
            if (mask_used(um, mstride, s) && tt >= 0 && tt < NREL) {
                const f32x4 w = *(const f32x4*)(x + (long)s * NCH + l * 4);
                #pragma unroll
                for (int q = 0; q < NREL; ++q) {
                    const float sel = (tt == q) ? 1.0f : 0.0f;
                    acc[q][0] += sel * w.x;
                    acc[q][1] += sel * w.y;
                    acc[q][2] += sel * w.z;
                    acc[q][3] += sel * w.w;
                }
            }
        }
        // bf16 pack -> swizzled LDS A[hw][k], k = q*128 + 4l + j
        #pragma unroll
        for (int q = 0; q < NREL; ++q) {
            ushort4 pkv;
            pkv.x = f2bf(acc[q][0]); pkv.y = f2bf(acc[q][1]);
            pkv.z = f2bf(acc[q][2]); pkv.w = f2bf(acc[q][3]);
            const int eb   = (q * NCH + l * 4) * 2;
            const int addr = (hw * 2048 + eb) ^ ((hw & 7) << 4);
            *(ushort4*)(As + addr) = pkv;
        }
    }
    __syncthreads();

    // MFMA: 8 waves; wave wv covers output cols [wv*16, wv*16+16)
    const int wv   = t >> 6;
    const int lane = t & 63;
    const int row  = lane & 15;
    const int koff = (lane >> 4) * 8;
    const int col0 = wv * 16 + row;
    f32x4 c0 = {0.f, 0.f, 0.f, 0.f};
    #pragma unroll 8
    for (int kt = 0; kt < 32; ++kt) {
        const int aaddr = (row * 2048 + (kt * 32 + koff) * 2) ^ ((row & 7) << 4);
        const bf16x8 a  = *(const bf16x8*)(As + aaddr);
        const bf16x8 b0 = *(const bf16x8*)(Wb + ((kt * NCH + col0) << 5) + koff);
        c0 = __builtin_amdgcn_mfma_f32_16x16x32_bf16(a, b0, c0, 0, 0, 0);
    }

    // epilogue: stage scaled C in LDS, store contiguous 512B rows (nt)
    __syncthreads();
    float* Cs = (float*)As;                // reuse As as float Cs[16][128]
    {
        const int r4 = (lane >> 4) * 4;
        #pragma unroll
        for (int j = 0; j < 4; ++j) {
            const int rr = r4 + j;
            Cs[rr * NCH + col0] = c0[j] * invdeg[rr];
        }
    }
    __syncthreads();
    {
        const int nn = nid[hw];
        if (nn >= 0) {
            const f32x4 vv = *(const f32x4*)(Cs + hw * NCH + l * 4);
            __builtin_nontemporal_store(vv,
                (f32x4*)(out + (long)nn * NCH + l * 4));
        }
    }
}

extern "C" void kernel_launch(void* const* d_in, const int* in_sizes, int n_in,
                              void* d_out, int out_size, void* d_ws, size_t ws_size,
                              hipStream_t stream) {
    const float*         x   = (const float*)d_in[0];
    const float*         W   = (const float*)d_in[1];
    const float*         hb  = (const float*)d_in[2];
    const int*           ptr = (const int*)d_in[3];
    const int*           idx = (const int*)d_in[4];
    const int*           et  = (const int*)d_in[5];
    const unsigned char* um  = (const unsigned char*)d_in[6];
    const int*           hm  = (const int*)d_in[7];
    const int*           hs  = (const int*)d_in[8];
    float* out = (float*)d_out;

    const int num_node = in_sizes[7];           // history_map length

    // ws layout: cn (2560B: [1]=mask width, [16+c*16]=tickets) | glist 32seg | Wb
    size_t off = 2560;
    int* cn    = (int*)d_ws;
    int* glist = (int*)((char*)d_ws + off);       off += (size_t)NSEG * SEGCAP * 4;
    unsigned short* Wb = (unsigned short*)((char*)d_ws + off);

    k_prep<<<(NREL * NCH * NCH + 255) / 256, 256, 0, stream>>>(W, Wb, cn, um);
    k_hist<<<(num_node + 31) / 32, 256, 0, stream>>>(hb, hm, hs, out, cn, glist, num_node);
    k_main<<<(num_node + 15) / 16, 512, 0, stream>>>(x, Wb, ptr, idx, et, um, cn, glist, out);
}

// Round 12
// 44.897 us; speedup vs baseline: 1.1345x; 1.1345x over previous
//
#include <hip/hip_runtime.h>
#include <hip/hip_bf16.h>
#include <stdint.h>

typedef __attribute__((ext_vector_type(4))) float f32x4;
typedef __attribute__((ext_vector_type(8))) short bf16x8;

#define NCH  128
#define NREL 8
#define NSEG 32            // ticket counters / glist segments
#define SEGCAP 2048        // max nodes per segment (32 windows x 64)

__device__ __forceinline__ unsigned short f2bf(float f) {
    unsigned u = __builtin_bit_cast(unsigned, f);
    u += 0x7fffu + ((u >> 16) & 1u);          // RNE to bf16
    return (unsigned short)(u >> 16);
}

__device__ __forceinline__ bool mask_used(const unsigned char* um, int stride, int s) {
    if (stride == 1) return um[s] != 0;
    if (stride == 4) return ((const int*)um)[s] != 0;
    return ((const long long*)um)[s] != 0;
}

// ---------------------------------------------------------------------------
// K1 (512 blocks x 256): Wb convert (1 elem/thread); blocks 0..255 also
// classify nodes: wave w handles window [b*256+w*64, +64), 64-lane ballot of
// non-cached, one ticket atomic per wave, compacted ids -> glist segment.
// Block 0 detects used_mask width -> cn[1]. Tickets pre-zeroed by memsetAsync.
// ---------------------------------------------------------------------------
__global__ __launch_bounds__(256)
void k_prep(const float* __restrict__ W, unsigned short* __restrict__ Wb,
            int* __restrict__ cn, const unsigned char* __restrict__ um_raw,
            const int* __restrict__ hm, const int* __restrict__ hs,
            int* __restrict__ glist, int num_node) {
    const int t = threadIdx.x;
    const int b = blockIdx.x;
    const int o = b * 256 + t;
    if (o < NREL * NCH * NCH) {
        const int kk  = o & 31;
        const int col = (o >> 5) & (NCH - 1);
        const int kt  = o >> 12;
        Wb[o] = f2bf(W[(kt * 32 + kk) * NCH + col]);
    }
    if (b < 256) {                                 // classification role
        const int w = t >> 6, l = t & 63;
        const int n = b * 256 + w * 64 + l;
        bool nc = false;
        if (n < num_node) nc = !((hs[0] > 0) && (hm[n] != -1));
        const unsigned long long m = __ballot(nc);
        const int cnt = __popcll(m);
        const int seg = (b * 4 + w) & (NSEG - 1);
        int base = 0;
        if (l == 0 && cnt) base = atomicAdd(&cn[16 + seg * 16], cnt);
        base = __shfl(base, 0, 64);
        if (nc)
            glist[seg * SEGCAP + base + __popcll(m & ((1ull << l) - 1))] = n;
    }
    if (b == 0) {                                  // mask width detect
        __shared__ unsigned sA, sB;
        if (t == 0) { sA = 0; sB = 0; }
        __syncthreads();
        unsigned a = 0, bb = 0;
        #pragma unroll 4
        for (int p = t; p < 1024; p += 256) {
            const unsigned v = um_raw[p];
            if ((p & 3) != 0) a |= v;   // bool kept 1B -> data off 4-align
            if ((p & 7) == 4) bb |= v;  // int32 -> data at 4 mod 8
        }
        if (a)  atomicOr(&sA, 1u);
        if (bb) atomicOr(&sB, 1u);
        __syncthreads();
        if (t == 0) cn[1] = sA ? 1 : (sB ? 4 : 8);
    }
}

// ---------------------------------------------------------------------------
// K2 (fused, 512 threads): blocks [0, mainSlots) = main role (R10 k_main
// verbatim: one node per half-wave, 16 gathers in flight, MFMA, LDS-staged
// epilogue). blocks [mainSlots, +copyBlocks) = copy role (64-node window:
// ballot cached list, 16 half-waves x 4 rounds of 512B row copies).
// Stream-bound copy blocks overlap latency-bound gather blocks on the CUs.
// ---------------------------------------------------------------------------
__global__ __launch_bounds__(512, 2)
void k_fused(const float* __restrict__ x, const unsigned short* __restrict__ Wb,
             const int* __restrict__ ptr, const int* __restrict__ idx,
             const int* __restrict__ et, const unsigned char* __restrict__ um,
             const int* __restrict__ cn, const int* __restrict__ glist,
             const float* __restrict__ hb, const int* __restrict__ hm,
             const int* __restrict__ hs, float* __restrict__ out,
             int num_node, int mainSlots) {
    __shared__ __align__(16) char As[16 * NREL * NCH * 2];   // 32 KB (main role)
    __shared__ int   nid[16];
    __shared__ float invdeg[16];
    __shared__ int   cList[64];
    __shared__ int   nC_s;

    const int t = threadIdx.x;

    if ((int)blockIdx.x >= mainSlots) {            // ---- copy role ----
        const int win = blockIdx.x - mainSlots;
        if (t < 64) {
            const int n = win * 64 + t;
            const bool cached = (n < num_node) && (hs[0] > 0) && (hm[n] != -1);
            const unsigned long long m = __ballot(cached);
            if (cached) cList[__popcll(m & ((1ull << t) - 1))] = n;
            if (t == 0) nC_s = __popcll(m);
        }
        __syncthreads();
        const int nC = nC_s;
        const int hw = t >> 5, l = t & 31;
        int   node[4];
        f32x4 v[4];
        #pragma unroll 4
        for (int j = 0; j < 4; ++j) {
            const int i = hw + j * 16;
            node[j] = (i < nC) ? cList[i] : -1;
            if (node[j] >= 0)
                v[j] = *(const f32x4*)(hb + (long)node[j] * NCH + l * 4);
        }
        #pragma unroll 4
        for (int j = 0; j < 4; ++j) {
            if (node[j] >= 0)
                __builtin_nontemporal_store(v[j],
                    (f32x4*)(out + (long)node[j] * NCH + l * 4));
        }
        return;
    }

    // ---- main role (R10 k_main verbatim) ----
    const int seg   = blockIdx.x & (NSEG - 1);
    const int grp   = blockIdx.x >> 5;
    const int cntS  = cn[16 + seg * 16];
    const int base  = grp * 16;
    if (base >= cntS) return;
    const int mstride = cn[1];
    if (t < 16) {
        const int i = base + t;
        nid[t]    = (i < cntS) ? glist[seg * SEGCAP + i] : -1;
        invdeg[t] = 0.0f;
    }
    __syncthreads();

    const int hw    = t >> 5;       // half-wave id 0..15 == node slot
    const int l     = t & 31;       // lane in half-wave; owns channels 4l..4l+3
    const int lbase = t & 32;       // half-wave base within its wave
    const int n     = nid[hw];

    if (n >= 0) {
        const int p0 = ptr[n], p1 = ptr[n + 1];
        const int deg = p1 - p0;
        if (l == 0) invdeg[hw] = (deg > 0) ? 1.0f / (float)deg : 0.0f;
        int myPk = NREL << 24;
        if (l < 16 && (p0 + l) < p1) {
            const int e  = p0 + l;
            const int s  = idx[e];
            const int tt = et[e];
            myPk = s | (((mask_used(um, mstride, s) && tt >= 0 && tt < NREL)
                         ? tt : NREL) << 24);
        }
        int   pk[16];
        f32x4 xv[16];
        #pragma unroll 16
        for (int e = 0; e < 16; ++e) {
            pk[e] = __shfl(myPk, lbase + e, 64);
            xv[e] = *(const f32x4*)(x + (long)(pk[e] & 0xFFFFFF) * NCH + l * 4);
        }
        float acc[NREL][4];
        #pragma unroll
        for (int q = 0; q < NREL; ++q)
            #pragma unroll
            for (int j = 0; j < 4; ++j) acc[q][j] = 0.0f;
        #pragma unroll 16
        for (int e = 0; e < 16; ++e) {
            const int r = pk[e] >> 24;
            #pragma unroll
            for (int q = 0; q < NREL; ++q) {
                const float sel = (r == q) ? 1.0f : 0.0f;
                acc[q][0] += sel * xv[e].x;
                acc[q][1] += sel * xv[e].y;
                acc[q][2] += sel * xv[e].z;
                acc[q][3] += sel * xv[e].w;
            }
        }
        for (int e = p0 + 16; e < p1; ++e) {       // rare: deg > 16
            const int s  = idx[e];
            const int tt = et[e];
            if (mask_used(um, mstride, s) && tt >= 0 && tt < NREL) {
                const f32x4 w = *(const f32x4*)(x + (long)s * NCH + l * 4);
                #pragma unroll
                for (int q = 0; q < NREL; ++q) {
                    const float sel = (tt == q) ? 1.0f : 0.0f;
                    acc[q][0] += sel * w.x;
                    acc[q][1] += sel * w.y;
                    acc[q][2] += sel * w.z;
                    acc[q][3] += sel * w.w;
                }
            }
        }
        #pragma unroll
        for (int q = 0; q < NREL; ++q) {
            ushort4 pkv;
            pkv.x = f2bf(acc[q][0]); pkv.y = f2bf(acc[q][1]);
            pkv.z = f2bf(acc[q][2]); pkv.w = f2bf(acc[q][3]);
            const int eb   = (q * NCH + l * 4) * 2;
            const int addr = (hw * 2048 + eb) ^ ((hw & 7) << 4);
            *(ushort4*)(As + addr) = pkv;
        }
    }
    __syncthreads();

    const int wv   = t >> 6;
    const int lane = t & 63;
    const int row  = lane & 15;
    const int koff = (lane >> 4) * 8;
    const int col0 = wv * 16 + row;
    f32x4 c0 = {0.f, 0.f, 0.f, 0.f};
    #pragma unroll 8
    for (int kt = 0; kt < 32; ++kt) {
        const int aaddr = (row * 2048 + (kt * 32 + koff) * 2) ^ ((row & 7) << 4);
        const bf16x8 a  = *(const bf16x8*)(As + aaddr);
        const bf16x8 b0 = *(const bf16x8*)(Wb + ((kt * NCH + col0) << 5) + koff);
        c0 = __builtin_amdgcn_mfma_f32_16x16x32_bf16(a, b0, c0, 0, 0, 0);
    }

    __syncthreads();
    float* Cs = (float*)As;                // reuse As as float Cs[16][128]
    {
        const int r4 = (lane >> 4) * 4;
        #pragma unroll
        for (int j = 0; j < 4; ++j) {
            const int rr = r4 + j;
            Cs[rr * NCH + col0] = c0[j] * invdeg[rr];
        }
    }
    __syncthreads();
    {
        const int nn = nid[hw];
        if (nn >= 0) {
            const f32x4 vv = *(const f32x4*)(Cs + hw * NCH + l * 4);
            __builtin_nontemporal_store(vv,
                (f32x4*)(out + (long)nn * NCH + l * 4));
        }
    }
}

extern "C" void kernel_launch(void* const* d_in, const int* in_sizes, int n_in,
                              void* d_out, int out_size, void* d_ws, size_t ws_size,
                              hipStream_t stream) {
    const float*         x   = (const float*)d_in[0];
    const float*         W   = (const float*)d_in[1];
    const float*         hb  = (const float*)d_in[2];
    const int*           ptr = (const int*)d_in[3];
    const int*           idx = (const int*)d_in[4];
    const int*           et  = (const int*)d_in[5];
    const unsigned char* um  = (const unsigned char*)d_in[6];
    const int*           hm  = (const int*)d_in[7];
    const int*           hs  = (const int*)d_in[8];
    float* out = (float*)d_out;

    const int num_node = in_sizes[7];           // history_map length

    // ws layout: cn (2560B: [1]=mask width, [16+c*16]=tickets) | glist 32seg | Wb
    size_t off = 2560;
    int* cn    = (int*)d_ws;
    int* glist = (int*)((char*)d_ws + off);       off += (size_t)NSEG * SEGCAP * 4;
    unsigned short* Wb = (unsigned short*)((char*)d_ws + off);

    const int mainSlots  = (num_node + 15) / 16;  // 4096
    const int copyBlocks = (num_node + 63) / 64;  // 1024

    hipMemsetAsync(cn, 0, 2560, stream);          // zero tickets each call
    k_prep<<<512, 256, 0, stream>>>(W, Wb, cn, um, hm, hs, glist, num_node);
    k_fused<<<mainSlots + copyBlocks, 512, 0, stream>>>(
        x, Wb, ptr, idx, et, um, cn, glist, hb, hm, hs, out, num_node, mainSlots);
}